// Round 15
// baseline (44.671 us; speedup 1.0000x reference)
//
#include <hip/hip_runtime.h>
#include <hip/hip_bf16.h>
#include <math.h>

#define QN 128
#define SN 128
#define HN 32
#define CN (QN * SN)
#define TILE_R 128   // batch rows per block

using half8   = __attribute__((ext_vector_type(8))) _Float16;
using floatx4 = __attribute__((ext_vector_type(4))) float;

// Grouped-GEMM via MFMA, no LDS, no barriers (R9 body). SINGLE CHANGE vs R9:
// x loads are NON-TEMPORAL (nt cache hint). x has zero reuse -- every byte is
// consumed exactly once device-wide -- so letting it allocate in L1/L2 only
// evicts W1[q] (the one high-reuse operand: 16 row-blocks re-read each W1
// line). nt keeps the x stream out of the cache-allocate path.
__global__ __launch_bounds__(256, 4)
void divenc_kernel(const float* __restrict__ x,
                   const float* __restrict__ W1,
                   const float* __restrict__ b1,
                   const float* __restrict__ W2,
                   const float* __restrict__ b2,
                   float* __restrict__ out) {
  const int q    = blockIdx.x;
  const int b0   = blockIdx.y * TILE_R;
  const int tid  = threadIdx.x;
  const int lane = tid & 63;
  const int wid  = __builtin_amdgcn_readfirstlane(tid >> 6);
  const int nA   = lane & 15;   // n-col / A-row within tile
  const int koct = lane >> 4;   // k-octet 0..3

  // ---- B-frags: lane holds W1[q][kk*32+koct*8+i][n0*16+nA] as fp16.
  const float* __restrict__ w1q = W1 + (size_t)q * (SN * HN);
  half8 bf[2][4];
  #pragma unroll
  for (int n0 = 0; n0 < 2; ++n0) {
    #pragma unroll
    for (int kk = 0; kk < 4; ++kk) {
      #pragma unroll
      for (int i = 0; i < 8; ++i) {
        const int k = kk * 32 + koct * 8 + i;
        bf[n0][kk][i] = (_Float16)w1q[k * HN + n0 * 16 + nA];
      }
    }
  }

  // ---- A-frags direct from global (non-temporal) + MFMA
  floatx4 z = {0.f, 0.f, 0.f, 0.f};
  floatx4 acc[2][2];
  acc[0][0] = z; acc[0][1] = z; acc[1][0] = z; acc[1][1] = z;

  const int row0 = b0 + wid * 32;
  #pragma unroll
  for (int mt = 0; mt < 2; ++mt) {
    const float* __restrict__ rp =
        x + (size_t)(row0 + mt * 16 + nA) * CN + q * SN + koct * 8;
    #pragma unroll
    for (int kk = 0; kk < 4; ++kk) {
      const floatx4 va = __builtin_nontemporal_load(
          reinterpret_cast<const floatx4*>(rp + kk * 32));
      const floatx4 vb = __builtin_nontemporal_load(
          reinterpret_cast<const floatx4*>(rp + kk * 32 + 4));
      half8 af;
      af[0] = (_Float16)va[0]; af[1] = (_Float16)va[1];
      af[2] = (_Float16)va[2]; af[3] = (_Float16)va[3];
      af[4] = (_Float16)vb[0]; af[5] = (_Float16)vb[1];
      af[6] = (_Float16)vb[2]; af[7] = (_Float16)vb[3];
      acc[mt][0] = __builtin_amdgcn_mfma_f32_16x16x32_f16(af, bf[0][kk], acc[mt][0], 0, 0, 0);
      acc[mt][1] = __builtin_amdgcn_mfma_f32_16x16x32_f16(af, bf[1][kk], acc[mt][1], 0, 0, 0);
    }
  }

  // ---- epilogue. C/D: col = nA, row (within tile) = koct*4 + reg.
  const float b1a = b1[q * HN + nA],  b1b = b1[q * HN + 16 + nA];
  const float w2a = W2[q * HN + nA],  w2b = W2[q * HN + 16 + nA];
  const float b2q = b2[q];

  #pragma unroll
  for (int mt = 0; mt < 2; ++mt) {
    #pragma unroll
    for (int reg = 0; reg < 4; ++reg) {
      float v0 = acc[mt][0][reg] + b1a;
      v0 = v0 > 0.f ? v0 : expm1f(v0);
      float v1 = acc[mt][1][reg] + b1b;
      v1 = v1 > 0.f ? v1 : expm1f(v1);
      float t = fmaf(v0, w2a, v1 * w2b);
      t += __shfl_xor(t, 1);
      t += __shfl_xor(t, 2);
      t += __shfl_xor(t, 4);
      t += __shfl_xor(t, 8);
      if (nA == 0) {
        const int row = row0 + mt * 16 + koct * 4 + reg;
        out[(size_t)row * QN + q] = t + b2q;
      }
    }
  }
}

extern "C" void kernel_launch(void* const* d_in, const int* in_sizes, int n_in,
                              void* d_out, int out_size, void* d_ws, size_t ws_size,
                              hipStream_t stream) {
  const float* x  = (const float*)d_in[0];
  const float* W1 = (const float*)d_in[1];
  const float* b1 = (const float*)d_in[2];
  const float* W2 = (const float*)d_in[3];
  const float* b2 = (const float*)d_in[4];
  float* out = (float*)d_out;

  const int B = in_sizes[0] / CN;  // 2048
  dim3 grid(QN, B / TILE_R);
  divenc_kernel<<<grid, 256, 0, stream>>>(x, W1, b1, W2, b2, out);
}

// Round 16
// 31.423 us; speedup vs baseline: 1.4216x; 1.4216x over previous
//
#include <hip/hip_runtime.h>
#include <hip/hip_bf16.h>
#include <math.h>

#define QN 128
#define SN 128
#define HN 32
#define CN (QN * SN)
#define TILE_R 64    // batch rows per block (16 per wave -> 1 M-tile)

using half8   = __attribute__((ext_vector_type(8))) _Float16;
using floatx4 = __attribute__((ext_vector_type(4))) float;

// Grouped-GEMM via MFMA, no LDS, no barriers. OCCUPANCY BUILD: targets
// 8 waves/SIMD (32/CU) -- VGPR must be <= 64 (m69: occupancy steps at 64/128).
// vs R9: TILE_R 128->64 (acc 16->8 regs), W1 B-frags gathered per-kk inside
// the loop (8 live regs, not 32), loads short-lived; expm1f -> __expf-1
// (no libm call; abs err ~1e-7 << 8.6e-2 threshold). Mechanism: R8-R14 all
// ran 4 waves/SIMD with loads in flight only ~40% of each wave's lifetime
// (load->drain->MFMA->epilogue serial); doubling resident waves fills the
// no-loads-in-flight gaps (MLP duty cycle), the surviving invariant theory.
__global__ __launch_bounds__(256, 8)
void divenc_kernel(const float* __restrict__ x,
                   const float* __restrict__ W1,
                   const float* __restrict__ b1,
                   const float* __restrict__ W2,
                   const float* __restrict__ b2,
                   float* __restrict__ out) {
  const int q    = blockIdx.x;
  const int b0   = blockIdx.y * TILE_R;
  const int tid  = threadIdx.x;
  const int lane = tid & 63;
  const int wid  = __builtin_amdgcn_readfirstlane(tid >> 6);
  const int nA   = lane & 15;   // A-row within M-tile / C col
  const int koct = lane >> 4;   // k-octet 0..3

  const float* __restrict__ w1q = W1 + (size_t)q * (SN * HN);
  const int row0 = b0 + wid * 16;

  floatx4 acc0 = {0.f, 0.f, 0.f, 0.f};
  floatx4 acc1 = {0.f, 0.f, 0.f, 0.f};

  const float* __restrict__ rp =
      x + (size_t)(row0 + nA) * CN + q * SN + koct * 8;

  #pragma unroll
  for (int kk = 0; kk < 4; ++kk) {
    // x A-frag: two float4 loads (16 rows x full lines, coalesced)
    const float4 va = *reinterpret_cast<const float4*>(rp + kk * 32);
    const float4 vb = *reinterpret_cast<const float4*>(rp + kk * 32 + 4);
    half8 af;
    af[0] = (_Float16)va.x; af[1] = (_Float16)va.y;
    af[2] = (_Float16)va.z; af[3] = (_Float16)va.w;
    af[4] = (_Float16)vb.x; af[5] = (_Float16)vb.y;
    af[6] = (_Float16)vb.z; af[7] = (_Float16)vb.w;

    // W1 B-frags for this kk only (8 live VGPRs)
    half8 bf0, bf1;
    #pragma unroll
    for (int i = 0; i < 8; ++i) {
      const int k = kk * 32 + koct * 8 + i;
      bf0[i] = (_Float16)w1q[k * HN + nA];
      bf1[i] = (_Float16)w1q[k * HN + 16 + nA];
    }

    acc0 = __builtin_amdgcn_mfma_f32_16x16x32_f16(af, bf0, acc0, 0, 0, 0);
    acc1 = __builtin_amdgcn_mfma_f32_16x16x32_f16(af, bf1, acc1, 0, 0, 0);
  }

  // ---- epilogue. C/D: col = nA, row (in tile) = koct*4 + reg.
  const float b1a = b1[q * HN + nA],  b1b = b1[q * HN + 16 + nA];
  const float w2a = W2[q * HN + nA],  w2b = W2[q * HN + 16 + nA];
  const float b2q = b2[q];

  #pragma unroll
  for (int reg = 0; reg < 4; ++reg) {
    float v0 = acc0[reg] + b1a;
    v0 = v0 > 0.f ? v0 : (__expf(v0) - 1.f);
    float v1 = acc1[reg] + b1b;
    v1 = v1 > 0.f ? v1 : (__expf(v1) - 1.f);
    float t = fmaf(v0, w2a, v1 * w2b);
    t += __shfl_xor(t, 1);
    t += __shfl_xor(t, 2);
    t += __shfl_xor(t, 4);
    t += __shfl_xor(t, 8);
    if (nA == 0) {
      const int row = row0 + koct * 4 + reg;
      out[(size_t)row * QN + q] = t + b2q;
    }
  }
}

extern "C" void kernel_launch(void* const* d_in, const int* in_sizes, int n_in,
                              void* d_out, int out_size, void* d_ws, size_t ws_size,
                              hipStream_t stream) {
  const float* x  = (const float*)d_in[0];
  const float* W1 = (const float*)d_in[1];
  const float* b1 = (const float*)d_in[2];
  const float* W2 = (const float*)d_in[3];
  const float* b2 = (const float*)d_in[4];
  float* out = (float*)d_out;

  const int B = in_sizes[0] / CN;  // 2048
  dim3 grid(QN, B / TILE_R);       // 128 x 32 = 4096 blocks, 8/CU
  divenc_kernel<<<grid, 256, 0, stream>>>(x, W1, b1, W2, b2, out);
}